// Round 14
// baseline (227.069 us; speedup 1.0000x reference)
//
#include <hip/hip_runtime.h>
#include <hip/hip_bf16.h>

#define BB 2
#define HH 56
#define WW 56
#define LL (HH*WW)          // 3136
#define DM 96
#define DI 192
#define NS 16               // d_state
#define DTR 6
#define KK 4
#define CDBL (DTR + 2*NS)   // 38
#define CS 32               // scan chunk size
#define NC 98               // number of chunks (CS*NC == LL)
#define ROWS (BB*KK*DI)     // 1536 state rows (x NS cols) per chunk

// ---------------- kernel 1: in_proj tiled GEMM, 64pos x 64ch blocks, 4x4 micro-tile ----------------
// grid (98, 6); LDS 51KB -> 3 blocks/CU. 8 b128 : 64 FMA per q (VALU-bound).
#define IP_BM 64
__global__ __launch_bounds__(256) void k_inproj(const float* __restrict__ x,
                                                const float* __restrict__ w,
                                                float* __restrict__ xcpre,
                                                float* __restrict__ zsilu) {
    __shared__ float xl[IP_BM*100];   // [pos][96], stride 100
    __shared__ float wl[64*100];      // j-interleaved: w-row r at lds row (r&3)*16+(r>>2)
    int t = threadIdx.x;
    int bl0 = blockIdx.x * IP_BM;
    int nc = blockIdx.y;
    int qs = t & 31;                  // staging q (0..23 active)
    for (int r = t >> 5; r < IP_BM; r += 8)
        if (qs < 24)
            *(float4*)&xl[r*100 + 4*qs] = *(const float4*)&x[(size_t)(bl0+r)*DM + 4*qs];
    for (int r = t >> 5; r < 64; r += 8)
        if (qs < 24)
            *(float4*)&wl[((r&3)*16 + (r>>2))*100 + 4*qs] =
                *(const float4*)&w[(size_t)(nc*64+r)*DM + 4*qs];
    __syncthreads();

    int pg = t >> 4, eg = t & 15;     // pg: 4 positions, eg: 4 channels (eg*4+jj)
    float acc[4][4] = {};
    const float4* xr0 = (const float4*)&xl[(pg*4+0)*100];
    const float4* xr1 = (const float4*)&xl[(pg*4+1)*100];
    const float4* xr2 = (const float4*)&xl[(pg*4+2)*100];
    const float4* xr3 = (const float4*)&xl[(pg*4+3)*100];
    const float4* w0 = (const float4*)&wl[(0*16+eg)*100];
    const float4* w1 = (const float4*)&wl[(1*16+eg)*100];
    const float4* w2 = (const float4*)&wl[(2*16+eg)*100];
    const float4* w3 = (const float4*)&wl[(3*16+eg)*100];
    #pragma unroll 4
    for (int q = 0; q < 24; ++q) {
        float4 xa = xr0[q], xb = xr1[q], xc = xr2[q], xd = xr3[q];
        float4 b0 = w0[q], b1 = w1[q], b2 = w2[q], b3 = w3[q];
        #define IP_FMA4(AJ, XA) \
            acc[AJ][0]=fmaf(XA.x,b0.x,acc[AJ][0]); acc[AJ][0]=fmaf(XA.y,b0.y,acc[AJ][0]); \
            acc[AJ][0]=fmaf(XA.z,b0.z,acc[AJ][0]); acc[AJ][0]=fmaf(XA.w,b0.w,acc[AJ][0]); \
            acc[AJ][1]=fmaf(XA.x,b1.x,acc[AJ][1]); acc[AJ][1]=fmaf(XA.y,b1.y,acc[AJ][1]); \
            acc[AJ][1]=fmaf(XA.z,b1.z,acc[AJ][1]); acc[AJ][1]=fmaf(XA.w,b1.w,acc[AJ][1]); \
            acc[AJ][2]=fmaf(XA.x,b2.x,acc[AJ][2]); acc[AJ][2]=fmaf(XA.y,b2.y,acc[AJ][2]); \
            acc[AJ][2]=fmaf(XA.z,b2.z,acc[AJ][2]); acc[AJ][2]=fmaf(XA.w,b2.w,acc[AJ][2]); \
            acc[AJ][3]=fmaf(XA.x,b3.x,acc[AJ][3]); acc[AJ][3]=fmaf(XA.y,b3.y,acc[AJ][3]); \
            acc[AJ][3]=fmaf(XA.z,b3.z,acc[AJ][3]); acc[AJ][3]=fmaf(XA.w,b3.w,acc[AJ][3]);
        IP_FMA4(0, xa) IP_FMA4(1, xb) IP_FMA4(2, xc) IP_FMA4(3, xd)
        #undef IP_FMA4
    }
    if (nc < 3) {
        #pragma unroll
        for (int j = 0; j < 4; ++j) {
            int bl = bl0 + pg*4 + j;
            #pragma unroll
            for (int jj = 0; jj < 4; ++jj)
                xcpre[(size_t)bl*DI + nc*64 + eg*4 + jj] = acc[j][jj];
        }
    } else {
        #pragma unroll
        for (int j = 0; j < 4; ++j) {
            int bl = bl0 + pg*4 + j;
            #pragma unroll
            for (int jj = 0; jj < 4; ++jj) {
                float v = acc[j][jj];
                zsilu[(size_t)bl*DI + (nc-3)*64 + eg*4 + jj] = v / (1.f + __expf(-v));
            }
        }
    }
}

// ------------- kernel 2: depthwise 3x3 conv + silu + scan scatter (no div) -------------
__global__ __launch_bounds__(DI) void k_conv(const float* __restrict__ xcpre,
                                             const float* __restrict__ cw,
                                             const float* __restrict__ cb,
                                             float* __restrict__ xs0,
                                             float* __restrict__ xs1) {
    int w = blockIdx.x, h = blockIdx.y, b = blockIdx.z;
    int c = threadIdx.x;
    const float* src = xcpre + ((size_t)(b*LL + h*WW + w))*DI + c;
    const float* cwc = cw + c*9;
    float acc = cb[c];
    if (h > 0) {
        if (w > 0)      acc = fmaf(src[-(WW+1)*DI], cwc[0], acc);
                        acc = fmaf(src[-WW*DI],     cwc[1], acc);
        if (w < WW-1)   acc = fmaf(src[-(WW-1)*DI], cwc[2], acc);
    }
    {
        if (w > 0)      acc = fmaf(src[-DI],        cwc[3], acc);
                        acc = fmaf(src[0],          cwc[4], acc);
        if (w < WW-1)   acc = fmaf(src[DI],         cwc[5], acc);
    }
    if (h < HH-1) {
        if (w > 0)      acc = fmaf(src[(WW-1)*DI],  cwc[6], acc);
                        acc = fmaf(src[WW*DI],      cwc[7], acc);
        if (w < WW-1)   acc = fmaf(src[(WW+1)*DI],  cwc[8], acc);
    }
    float v = acc / (1.f + __expf(-acc));   // silu
    int i  = (w & 1) ? (HH-1-h) : h;
    int l0 = i*WW + w;
    int l1 = ((i & 1) ? (WW-1-w) : w)*HH + i;
    xs0[((size_t)b*LL + l0)*DI + c] = v;
    xs1[((size_t)b*LL + l1)*DI + c] = v;
}

// ------------- kernel 3: x_proj + dt_proj + softplus (single-stage, 2 barriers) -------------
#define TL 32
#define PSTR 196            // LDS row stride (floats); bank stride 196%32=4
__global__ __launch_bounds__(256) void k_proj(const float* __restrict__ xs0,
                                              const float* __restrict__ xs1,
                                              const float* __restrict__ xpw,   // (K,38,192)
                                              const float* __restrict__ dtw,   // (K,192,6)
                                              const float* __restrict__ dtb,   // (K,192)
                                              float* __restrict__ delta,
                                              float* __restrict__ Bsb,
                                              float* __restrict__ Csb) {
    int tile = blockIdx.x, k = blockIdx.y, b = blockIdx.z;
    int bk = b*KK + k;
    int t = threadIdx.x;
    __shared__ float Wl[39*PSTR];      // 38 rows + zero row 38 (30.6KB)
    __shared__ float Xl[TL*PSTR];      // 32 rows full 192 (25.1KB)
    __shared__ float dblL[DTR*36];

    const float* src = (k & 1) ? xs1 : xs0;
    const bool rev = (k >= 2);
    int cp = t >> 4, lp = t & 15;
    int qs = t & 15;                   // staging lane (0..11 active)

    // stage Wl once (38 rows x 48 float4; row 38 zero)
    for (int r = t >> 4; r < 39; r += 16)
        if (qs < 12) {
            #pragma unroll
            for (int c4 = 0; c4 < 4; ++c4) {
                int q = qs + 12*c4;
                float4 v = (r < CDBL)
                    ? *(const float4*)&xpw[(size_t)k*CDBL*DI + (size_t)r*DI + 4*q]
                    : make_float4(0.f,0.f,0.f,0.f);
                *(float4*)&Wl[r*PSTR + 4*q] = v;
            }
        }
    // stage Xl once (32 rows x 48 float4)
    for (int r = t >> 4; r < TL; r += 16)
        if (qs < 12) {
            int lg = tile*TL + r;
            int lpos = rev ? (LL-1-lg) : lg;
            const float4* s4 = (const float4*)&src[(size_t)(b*LL + lpos)*DI];
            #pragma unroll
            for (int c4 = 0; c4 < 4; ++c4) {
                int q = qs + 12*c4;
                *(float4*)&Xl[r*PSTR + 4*q] = s4[q];
            }
        }
    __syncthreads();

    // single compute phase: 3c x 2l micro-tile, q 0..47
    if (cp < 13) {
        float acc[3][2] = {};
        const float4* w0 = (const float4*)&Wl[(3*cp+0)*PSTR];
        const float4* w1 = (const float4*)&Wl[(3*cp+1)*PSTR];
        const float4* w2 = (const float4*)&Wl[(3*cp+2)*PSTR];
        const float4* x0 = (const float4*)&Xl[(lp    )*PSTR];
        const float4* x1 = (const float4*)&Xl[(lp+16)*PSTR];
        #pragma unroll 8
        for (int q = 0; q < 48; ++q) {
            float4 wa = w0[q], wb = w1[q], wc = w2[q];
            float4 xa = x0[q], xb = x1[q];
            acc[0][0]=fmaf(wa.x,xa.x,acc[0][0]); acc[0][0]=fmaf(wa.y,xa.y,acc[0][0]);
            acc[0][0]=fmaf(wa.z,xa.z,acc[0][0]); acc[0][0]=fmaf(wa.w,xa.w,acc[0][0]);
            acc[0][1]=fmaf(wa.x,xb.x,acc[0][1]); acc[0][1]=fmaf(wa.y,xb.y,acc[0][1]);
            acc[0][1]=fmaf(wa.z,xb.z,acc[0][1]); acc[0][1]=fmaf(wa.w,xb.w,acc[0][1]);
            acc[1][0]=fmaf(wb.x,xa.x,acc[1][0]); acc[1][0]=fmaf(wb.y,xa.y,acc[1][0]);
            acc[1][0]=fmaf(wb.z,xa.z,acc[1][0]); acc[1][0]=fmaf(wb.w,xa.w,acc[1][0]);
            acc[1][1]=fmaf(wb.x,xb.x,acc[1][1]); acc[1][1]=fmaf(wb.y,xb.y,acc[1][1]);
            acc[1][1]=fmaf(wb.z,xb.z,acc[1][1]); acc[1][1]=fmaf(wb.w,xb.w,acc[1][1]);
            acc[2][0]=fmaf(wc.x,xa.x,acc[2][0]); acc[2][0]=fmaf(wc.y,xa.y,acc[2][0]);
            acc[2][0]=fmaf(wc.z,xa.z,acc[2][0]); acc[2][0]=fmaf(wc.w,xa.w,acc[2][0]);
            acc[2][1]=fmaf(wc.x,xb.x,acc[2][1]); acc[2][1]=fmaf(wc.y,xb.y,acc[2][1]);
            acc[2][1]=fmaf(wc.z,xb.z,acc[2][1]); acc[2][1]=fmaf(wc.w,xb.w,acc[2][1]);
        }
        #pragma unroll
        for (int ci = 0; ci < 3; ++ci) {
            int c = 3*cp + ci;
            if (c < CDBL) {
                #pragma unroll
                for (int li = 0; li < 2; ++li) {
                    int ll = lp + 16*li;
                    int lg = tile*TL + ll;
                    float v = acc[ci][li];
                    if (c < DTR)          dblL[c*36 + ll] = v;
                    else if (c < DTR+NS)  Bsb[((size_t)bk*LL + lg)*NS + (c-DTR)] = v;
                    else                  Csb[((size_t)bk*LL + lg)*NS + (c-DTR-NS)] = v;
                }
            }
        }
    }
    __syncthreads();

    // phase 2: thread = d (192 active), acc[32] in regs, fast softplus
    if (t < DI) {
        int d = t;
        float wr[DTR];
        #pragma unroll
        for (int r = 0; r < DTR; ++r) wr[r] = dtw[((size_t)k*DI + d)*DTR + r];
        float bias = dtb[k*DI + d];
        float a2[TL];
        #pragma unroll
        for (int ll = 0; ll < TL; ++ll) a2[ll] = bias;
        #pragma unroll
        for (int r = 0; r < DTR; ++r) {
            float wv = wr[r];
            const float4* db = (const float4*)&dblL[r*36];
            #pragma unroll
            for (int q = 0; q < 8; ++q) {
                float4 v = db[q];
                a2[4*q+0] = fmaf(wv, v.x, a2[4*q+0]);
                a2[4*q+1] = fmaf(wv, v.y, a2[4*q+1]);
                a2[4*q+2] = fmaf(wv, v.z, a2[4*q+2]);
                a2[4*q+3] = fmaf(wv, v.w, a2[4*q+3]);
            }
        }
        float* dst = delta + ((size_t)bk*LL + (size_t)tile*TL)*DI + d;
        #pragma unroll
        for (int ll = 0; ll < TL; ++ll) {
            float a = a2[ll];
            float sp = fmaxf(a, 0.f) + __logf(1.f + __expf(-fabsf(a)));
            dst[ll*DI] = sp;
        }
    }
}

// ------------- kernel 4a: chunked scan pass 1 — thread = d, 16 n-states in regs -------------
__global__ __launch_bounds__(192) void k_scan1(const float* __restrict__ delta,
                                               const float* __restrict__ xs0,
                                               const float* __restrict__ xs1,
                                               const float* __restrict__ Bsb,
                                               const float* __restrict__ A_logs,
                                               float* __restrict__ P,     // [c][bk*DI+d][n]
                                               float* __restrict__ Hend) {
    int c = blockIdx.x, bk = blockIdx.y;
    int k = bk & 3, b = bk >> 2;
    int d = threadIdx.x;
    int kd = k*DI + d;
    __shared__ float Bl[CS*NS];
    const float* bsrc = Bsb + ((size_t)bk*LL + c*CS)*NS;
    for (int i = threadIdx.x; i < CS*NS/4; i += 192)
        ((float4*)Bl)[i] = ((const float4*)bsrc)[i];

    float A[NS], h[NS], p[NS];
    #pragma unroll
    for (int q = 0; q < 4; ++q) {
        float4 av = *(const float4*)&A_logs[kd*NS + 4*q];
        A[4*q+0] = -expf(av.x); A[4*q+1] = -expf(av.y);
        A[4*q+2] = -expf(av.z); A[4*q+3] = -expf(av.w);
    }
    #pragma unroll
    for (int n = 0; n < NS; ++n) { h[n] = 0.f; p[n] = 1.f; }
    __syncthreads();

    const bool rev = (k >= 2);
    const float* dp = delta + ((size_t)bk*LL + c*CS)*DI + d;
    const float* up = ((k & 1) ? xs1 : xs0) + (size_t)b*LL*DI + d;
    const int l0 = c*CS;

    #pragma unroll 2
    for (int i = 0; i < CS; ++i) {
        float dt = dp[(size_t)i*DI];
        int lp = rev ? (LL-1-(l0+i)) : (l0+i);
        float u = up[(size_t)lp*DI];
        float dtu = dt * u;
        float Bv[NS];
        #pragma unroll
        for (int q = 0; q < 4; ++q)
            *(float4*)&Bv[4*q] = *(const float4*)&Bl[i*NS + 4*q];
        #pragma unroll
        for (int n = 0; n < NS; ++n) {
            float dA = __expf(dt * A[n]);
            h[n] = fmaf(dA, h[n], dtu * Bv[n]);
            p[n] *= dA;
        }
    }
    size_t obase = ((size_t)c*ROWS + bk*DI + d)*NS;
    #pragma unroll
    for (int q = 0; q < 4; ++q) {
        *(float4*)&P[obase + 4*q]    = make_float4(p[4*q], p[4*q+1], p[4*q+2], p[4*q+3]);
        *(float4*)&Hend[obase + 4*q] = make_float4(h[4*q], h[4*q+1], h[4*q+2], h[4*q+3]);
    }
}

// ------------- kernel 4b: combine chunk states sequentially -------------
__global__ __launch_bounds__(256) void k_scanmid(const float* __restrict__ P,
                                                 const float* __restrict__ Hend,
                                                 float* __restrict__ Hin) {
    int tid = blockIdx.x*256 + threadIdx.x;     // 0 .. ROWS*NS-1
    float h = 0.f;
    for (int c = 0; c < NC; ++c) {
        size_t idx = (size_t)c*(ROWS*NS) + tid;
        Hin[idx] = h;
        h = fmaf(P[idx], h, Hend[idx]);
    }
}

// ------------- kernel 4c: chunked scan pass 2 — rescan with true h_in, emit y -------------
__global__ __launch_bounds__(192) void k_scan2(const float* __restrict__ delta,
                                               const float* __restrict__ xs0,
                                               const float* __restrict__ xs1,
                                               const float* __restrict__ Bsb,
                                               const float* __restrict__ Csb,
                                               const float* __restrict__ A_logs,
                                               const float* __restrict__ Ds,
                                               const float* __restrict__ Hin,
                                               float* __restrict__ oy) {
    int c = blockIdx.x, bk = blockIdx.y;
    int k = bk & 3, b = bk >> 2;
    int d = threadIdx.x;
    int kd = k*DI + d;
    __shared__ float Bl[CS*NS];
    __shared__ float Cl[CS*NS];
    const float* bsrc = Bsb + ((size_t)bk*LL + c*CS)*NS;
    const float* csrc = Csb + ((size_t)bk*LL + c*CS)*NS;
    for (int i = threadIdx.x; i < CS*NS/4; i += 192) {
        ((float4*)Bl)[i] = ((const float4*)bsrc)[i];
        ((float4*)Cl)[i] = ((const float4*)csrc)[i];
    }

    float A[NS], h[NS];
    #pragma unroll
    for (int q = 0; q < 4; ++q) {
        float4 av = *(const float4*)&A_logs[kd*NS + 4*q];
        A[4*q+0] = -expf(av.x); A[4*q+1] = -expf(av.y);
        A[4*q+2] = -expf(av.z); A[4*q+3] = -expf(av.w);
    }
    size_t ibase = ((size_t)c*ROWS + bk*DI + d)*NS;
    #pragma unroll
    for (int q = 0; q < 4; ++q) {
        float4 hv = *(const float4*)&Hin[ibase + 4*q];
        h[4*q+0] = hv.x; h[4*q+1] = hv.y; h[4*q+2] = hv.z; h[4*q+3] = hv.w;
    }
    const float Dv = Ds[kd];
    __syncthreads();

    const bool rev = (k >= 2);
    const float* dp = delta + ((size_t)bk*LL + c*CS)*DI + d;
    const float* up = ((k & 1) ? xs1 : xs0) + (size_t)b*LL*DI + d;
    float* yp = oy + ((size_t)bk*LL + c*CS)*DI + d;
    const int l0 = c*CS;

    #pragma unroll 2
    for (int i = 0; i < CS; ++i) {
        float dt = dp[(size_t)i*DI];
        int lp = rev ? (LL-1-(l0+i)) : (l0+i);
        float u = up[(size_t)lp*DI];
        float dtu = dt * u;
        float Bv[NS], Cv[NS];
        #pragma unroll
        for (int q = 0; q < 4; ++q) {
            *(float4*)&Bv[4*q] = *(const float4*)&Bl[i*NS + 4*q];
            *(float4*)&Cv[4*q] = *(const float4*)&Cl[i*NS + 4*q];
        }
        float acc = 0.f;
        #pragma unroll
        for (int n = 0; n < NS; ++n) {
            float dA = __expf(dt * A[n]);
            h[n] = fmaf(dA, h[n], dtu * Bv[n]);
            acc = fmaf(h[n], Cv[n], acc);
        }
        yp[(size_t)i*DI] = fmaf(u, Dv, acc);
    }
}

// ------------- kernel 5: gather + LayerNorm + gate, then float4 GEMM out_proj -------------
#define OP_BM 32
__global__ __launch_bounds__(256) void k_out(const float* __restrict__ oy,
                                             const float* __restrict__ zsilu,
                                             const float* __restrict__ onw,
                                             const float* __restrict__ onb,
                                             const float* __restrict__ opw,
                                             float* __restrict__ out) {
    __shared__ float yv[OP_BM*196];
    __shared__ float wl[96*68];
    int t = threadIdx.x;
    int bl0 = blockIdx.x * OP_BM;
    int b = (blockIdx.x >= (LL/OP_BM)) ? 1 : 0;   // uniform, no div
    int lbase = bl0 - b*LL;
    int lane = t & 63, wv = t >> 6;

    for (int pp = 0; pp < 8; ++pp) {
        int p = wv*8 + pp;
        int l = lbase + p;
        int h = l / WW, w2 = l % WW;              // const-div -> mulhi
        int i = (w2 & 1) ? (HH-1-h) : h;
        int l0 = i*WW + w2;
        int l1 = ((i & 1) ? (WW-1-w2) : w2)*HH + i;
        size_t base = (size_t)b*KK*LL*DI;
        float yd[3]; float s1 = 0.f, s2 = 0.f;
        #pragma unroll
        for (int j = 0; j < 3; ++j) {
            int c = lane + j*64;
            float v = oy[base + (size_t)(0*LL + l0)*DI + c]
                    + oy[base + (size_t)(1*LL + l1)*DI + c]
                    + oy[base + (size_t)(2*LL + (LL-1-l0))*DI + c]
                    + oy[base + (size_t)(3*LL + (LL-1-l1))*DI + c];
            yd[j] = v; s1 += v; s2 += v*v;
        }
        #pragma unroll
        for (int m = 1; m < 64; m <<= 1) { s1 += __shfl_xor(s1, m); s2 += __shfl_xor(s2, m); }
        float mu  = s1 / DI;
        float var = s2 / DI - mu*mu;
        float ry  = rsqrtf(var + 1e-5f);
        #pragma unroll
        for (int j = 0; j < 3; ++j) {
            int c = lane + j*64;
            float yn = (yd[j] - mu) * ry * onw[c] + onb[c];
            yv[p*196 + c] = yn * zsilu[(size_t)(bl0+p)*DI + c];
        }
    }

    // phase B: 4p x 3e float4 micro-tile over 3 k-chunks of 64
    int pg = t >> 5, eg = t & 31;     // pg: 4 positions, eg: 3 channels
    float acc[4][3] = {};
    for (int kc = 0; kc < 3; ++kc) {
        __syncthreads();
        for (int r = t >> 4; r < 96; r += 16)
            *(float4*)&wl[r*68 + 4*(t&15)] =
                *(const float4*)&opw[(size_t)r*DI + kc*64 + 4*(t&15)];
        __syncthreads();
        const float4* y0 = (const float4*)&yv[(pg*4+0)*196 + kc*64];
        const float4* y1 = (const float4*)&yv[(pg*4+1)*196 + kc*64];
        const float4* y2 = (const float4*)&yv[(pg*4+2)*196 + kc*64];
        const float4* y3 = (const float4*)&yv[(pg*4+3)*196 + kc*64];
        const float4* w0 = (const float4*)&wl[(eg*3+0)*68];
        const float4* w1 = (const float4*)&wl[(eg*3+1)*68];
        const float4* w2 = (const float4*)&wl[(eg*3+2)*68];
        #pragma unroll
        for (int q = 0; q < 16; ++q) {
            float4 a0 = y0[q], a1 = y1[q], a2 = y2[q], a3 = y3[q];
            float4 b0 = w0[q], b1 = w1[q], b2 = w2[q];
            acc[0][0]=fmaf(a0.x,b0.x,acc[0][0]); acc[0][0]=fmaf(a0.y,b0.y,acc[0][0]);
            acc[0][0]=fmaf(a0.z,b0.z,acc[0][0]); acc[0][0]=fmaf(a0.w,b0.w,acc[0][0]);
            acc[0][1]=fmaf(a0.x,b1.x,acc[0][1]); acc[0][1]=fmaf(a0.y,b1.y,acc[0][1]);
            acc[0][1]=fmaf(a0.z,b1.z,acc[0][1]); acc[0][1]=fmaf(a0.w,b1.w,acc[0][1]);
            acc[0][2]=fmaf(a0.x,b2.x,acc[0][2]); acc[0][2]=fmaf(a0.y,b2.y,acc[0][2]);
            acc[0][2]=fmaf(a0.z,b2.z,acc[0][2]); acc[0][2]=fmaf(a0.w,b2.w,acc[0][2]);
            acc[1][0]=fmaf(a1.x,b0.x,acc[1][0]); acc[1][0]=fmaf(a1.y,b0.y,acc[1][0]);
            acc[1][0]=fmaf(a1.z,b0.z,acc[1][0]); acc[1][0]=fmaf(a1.w,b0.w,acc[1][0]);
            acc[1][1]=fmaf(a1.x,b1.x,acc[1][1]); acc[1][1]=fmaf(a1.y,b1.y,acc[1][1]);
            acc[1][1]=fmaf(a1.z,b1.z,acc[1][1]); acc[1][1]=fmaf(a1.w,b1.w,acc[1][1]);
            acc[1][2]=fmaf(a1.x,b2.x,acc[1][2]); acc[1][2]=fmaf(a1.y,b2.y,acc[1][2]);
            acc[1][2]=fmaf(a1.z,b2.z,acc[1][2]); acc[1][2]=fmaf(a1.w,b2.w,acc[1][2]);
            acc[2][0]=fmaf(a2.x,b0.x,acc[2][0]); acc[2][0]=fmaf(a2.y,b0.y,acc[2][0]);
            acc[2][0]=fmaf(a2.z,b0.z,acc[2][0]); acc[2][0]=fmaf(a2.w,b0.w,acc[2][0]);
            acc[2][1]=fmaf(a2.x,b1.x,acc[2][1]); acc[2][1]=fmaf(a2.y,b1.y,acc[2][1]);
            acc[2][1]=fmaf(a2.z,b1.z,acc[2][1]); acc[2][1]=fmaf(a2.w,b1.w,acc[2][1]);
            acc[2][2]=fmaf(a2.x,b2.x,acc[2][2]); acc[2][2]=fmaf(a2.y,b2.y,acc[2][2]);
            acc[2][2]=fmaf(a2.z,b2.z,acc[2][2]); acc[2][2]=fmaf(a2.w,b2.w,acc[2][2]);
            acc[3][0]=fmaf(a3.x,b0.x,acc[3][0]); acc[3][0]=fmaf(a3.y,b0.y,acc[3][0]);
            acc[3][0]=fmaf(a3.z,b0.z,acc[3][0]); acc[3][0]=fmaf(a3.w,b0.w,acc[3][0]);
            acc[3][1]=fmaf(a3.x,b1.x,acc[3][1]); acc[3][1]=fmaf(a3.y,b1.y,acc[3][1]);
            acc[3][1]=fmaf(a3.z,b1.z,acc[3][1]); acc[3][1]=fmaf(a3.w,b1.w,acc[3][1]);
            acc[3][2]=fmaf(a3.x,b2.x,acc[3][2]); acc[3][2]=fmaf(a3.y,b2.y,acc[3][2]);
            acc[3][2]=fmaf(a3.z,b2.z,acc[3][2]); acc[3][2]=fmaf(a3.w,b2.w,acc[3][2]);
        }
    }
    #pragma unroll
    for (int j = 0; j < 4; ++j) {
        int bl = bl0 + pg*4 + j;
        #pragma unroll
        for (int jj = 0; jj < 3; ++jj)
            out[(size_t)bl*DM + eg*3 + jj] = acc[j][jj];
    }
}

extern "C" void kernel_launch(void* const* d_in, const int* in_sizes, int n_in,
                              void* d_out, int out_size, void* d_ws, size_t ws_size,
                              hipStream_t stream) {
    const float* x      = (const float*)d_in[0];
    const float* ipw    = (const float*)d_in[1];
    const float* convw  = (const float*)d_in[2];
    const float* convb  = (const float*)d_in[3];
    const float* xpw    = (const float*)d_in[4];
    const float* dtw    = (const float*)d_in[5];
    const float* dtb    = (const float*)d_in[6];
    const float* A_logs = (const float*)d_in[7];
    const float* Ds     = (const float*)d_in[8];
    const float* onw    = (const float*)d_in[9];
    const float* onb    = (const float*)d_in[10];
    const float* opw    = (const float*)d_in[11];
    float* out = (float*)d_out;

    float* ws = (float*)d_ws;
    const size_t SZ_BLD  = (size_t)BB*LL*DI;          // 1,204,224
    const size_t SZ_BKLD = (size_t)BB*KK*LL*DI;       // 4,816,896
    const size_t SZ_BKLN = (size_t)BB*KK*LL*NS;       //   401,408
    const size_t SZ_ST   = (size_t)NC*ROWS*NS;        // 2,408,448
    float* xcpre = ws;
    float* zsilu = xcpre + SZ_BLD;
    float* xs0   = zsilu + SZ_BLD;
    float* xs1   = xs0   + SZ_BLD;
    float* delta = xs1   + SZ_BLD;
    float* Bsb   = delta + SZ_BKLD;
    float* Csb   = Bsb   + SZ_BKLN;
    float* oy    = Csb   + SZ_BKLN;
    float* Hin   = oy    + SZ_BKLD;
    float* Hend  = oy;                // alias: dead before oy written (scan2)
    float* P     = oy + SZ_ST;        // alias: 2*SZ_ST == SZ_BKLD, fits exactly

    k_inproj<<<dim3((BB*LL)/IP_BM, 6), 256, 0, stream>>>(x, ipw, xcpre, zsilu);
    k_conv<<<dim3(WW, HH, BB), DI, 0, stream>>>(xcpre, convw, convb, xs0, xs1);
    dim3 g3(LL/TL, KK, BB);
    k_proj<<<g3, 256, 0, stream>>>(xs0, xs1, xpw, dtw, dtb, delta, Bsb, Csb);
    dim3 gs(NC, BB*KK);
    k_scan1<<<gs, 192, 0, stream>>>(delta, xs0, xs1, Bsb, A_logs, P, Hend);
    k_scanmid<<<(ROWS*NS)/256, 256, 0, stream>>>(P, Hend, Hin);
    k_scan2<<<gs, 192, 0, stream>>>(delta, xs0, xs1, Bsb, Csb, A_logs, Ds, Hin, oy);
    k_out<<<(BB*LL)/OP_BM, 256, 0, stream>>>(oy, zsilu, onw, onb, opw, out);
}